// Round 16
// baseline (143.976 us; speedup 1.0000x reference)
//
#include <hip/hip_runtime.h>
#include <hip/hip_bf16.h>

#define B_   16384
#define KIN  512
#define NE   8
#define HE   256
#define NT   2
#define NO   64

using f32x4  = __attribute__((ext_vector_type(4))) float;
using short8 = __attribute__((ext_vector_type(8))) short;

__device__ __forceinline__ float bf2f(unsigned short u) {
    union { unsigned int i; float f; } c; c.i = ((unsigned int)u) << 16; return c.f;
}
__device__ __forceinline__ unsigned short f2bf(float f) {
    union { __hip_bfloat16 h; unsigned short u; } c; c.h = __float2bfloat16(f); return c.u;
}

// ---------------- K_W: weight preprocessing (r11 fragment-major, verified r11-r13) ----------------
// bid < 256: We [E][K][H] -> Wb2 FRAGMENT-MAJOR bf16:
//   Wb2[((((s*2+kk)*8+hg)*2+nf)*64+lane)*8+j] = We[e][kt*64+kk*32+(lane>>4)*8+j][hg*32+nf*16+(lane&15)]
//   with s = e*8+kt. One wave's (s,kk,nf) fragment = contiguous 1KB -> coalesced L2 load.
// bid 256..263: Wt -> WtT bf16 [T][NO][HE];  bid 264: Wg -> WgT bf16 [16][KIN]
__global__ __launch_bounds__(256) void k_cvt_w(const float* __restrict__ We,
                                               const float* __restrict__ Wt,
                                               const float* __restrict__ Wg,
                                               unsigned short* __restrict__ Wb2,
                                               unsigned short* __restrict__ WtT,
                                               unsigned short* __restrict__ WgT) {
    int bid = blockIdx.x;
    int tid = threadIdx.x;
    if (bid < 256) {
        __shared__ float tile[64][65];
        int e = bid >> 5, rem = bid & 31, kt = rem >> 2, ht = rem & 3;
        const float* src = We + e * (KIN * HE) + (kt * 64) * HE + ht * 64;
        for (int it = 0; it < 16; ++it) {
            int idx = tid + it * 256;
            int i = idx >> 6, j = idx & 63;          // i = k-sub, j = h-sub
            tile[i][j] = src[i * HE + j];
        }
        __syncthreads();
        int s = e * 8 + kt;
        for (int it = 0; it < 16; ++it) {
            int o = tid + it * 256;                  // 0..4095 output-linear
            int j = o & 7, lane = (o >> 3) & 63;
            int nf = (o >> 9) & 1, wavl = (o >> 10) & 1, kk = (o >> 11) & 1;
            int l4 = lane >> 4, l15 = lane & 15;
            int ksub = kk * 32 + l4 * 8 + j;
            int hsub = wavl * 32 + nf * 16 + l15;
            size_t F = ((((size_t)(s * 2 + kk) * 8 + (ht * 2 + wavl)) * 2 + nf) * 64 + lane) * 8 + j;
            Wb2[F] = f2bf(tile[ksub][hsub]);
        }
    } else if (bid < 264) {
        __shared__ float tile[64][65];
        int b = bid - 256;
        int t = b >> 2, kt = b & 3, k0 = kt * 64;
        const float* src = Wt + t * (HE * NO) + k0 * NO;
        for (int it = 0; it < 16; ++it) {
            int idx = tid + it * 256;
            int i = idx >> 6, j = idx & 63;
            tile[i][j] = src[i * NO + j];
        }
        __syncthreads();
        unsigned short* dst = WtT + (size_t)t * NO * HE + k0;
        for (int it = 0; it < 16; ++it) {
            int idx = tid + it * 256;
            int o = idx >> 6, j = idx & 63;
            dst[o * HE + j] = f2bf(tile[j][o]);
        }
    } else {
        int n = tid >> 4;
        int kb = (tid & 15) * 32;
        int t = n >> 3, e = n & 7;
        const float* src = Wg + t * (KIN * NE) + e;
        for (int j = 0; j < 32; ++j) {
            int k = kb + j;
            WgT[n * KIN + k] = f2bf(src[k * NE]);
        }
    }
}

// ---------------- K_MEGA: cvt_x + gates + experts + mix + tower ----------------
// r10 register profile (acc32+ti64, VGPR ~92, no loop-carried B) but B fragments
// come TRANSIENTLY from L2 each step (fragment-major Wb2) instead of LDS:
// deletes stage_b DMA, B ds_reads, vmcnt pacing — LDS pipe serves only A.
// bb[] is declared inside the loop body (same lifetime as r10's LDS-read bb),
// so this does NOT reintroduce the r11-r14 spill (persistent B state falsified).
// LDS: Xs 64KB (swizzled) + gs 4.25KB; TIs overlays after the loop.
__global__ __launch_bounds__(512, 2) void k_mega(const float* __restrict__ xv,
                                                 const unsigned short* __restrict__ Wb2,
                                                 const float* __restrict__ be,
                                                 const unsigned short* __restrict__ WgT,
                                                 const float* __restrict__ bg,
                                                 const unsigned short* __restrict__ WtT,
                                                 const float* __restrict__ bt,
                                                 float* __restrict__ out) {
    __shared__ __align__(16) char smem[69888];
    unsigned short* Xs  = (unsigned short*)smem;             // 65536 B, swizzled
    float*          gs  = (float*)(smem + 65536);            // 4352 B, row stride 17
    unsigned short* TIs = (unsigned short*)smem;             // overlay after loop

    int tid = threadIdx.x, lane = tid & 63, wav = tid >> 6;
    int l15 = lane & 15, l4 = lane >> 4;
    int swz = (l15 & 7) * 8;                 // read-side XOR (shorts)
    int wv32 = wav * 32;                     // wave's h-col slice
    int r0 = blockIdx.x * 64;

    // ---- prologue: X fp32 -> bf16 -> swizzled LDS (reg-staged)
    #pragma unroll
    for (int j = 0; j < 8; ++j) {
        int row = wav * 8 + j;
        const float4* src = (const float4*)(xv + (size_t)(r0 + row) * KIN) + lane * 2;
        float4 xa = src[0], xb = src[1];
        union { short8 v; unsigned short s[8]; } cv;
        cv.s[0] = f2bf(xa.x); cv.s[1] = f2bf(xa.y); cv.s[2] = f2bf(xa.z); cv.s[3] = f2bf(xa.w);
        cv.s[4] = f2bf(xb.x); cv.s[5] = f2bf(xb.y); cv.s[6] = f2bf(xb.z); cv.s[7] = f2bf(xb.w);
        *(short8*)(Xs + row * KIN + ((lane ^ (row & 7)) * 8)) = cv.v;
    }
    __syncthreads();                                 // Xs visible

    // ---- gates: softmax(X @ WgT^T + bg) -> gs  (waves w, w+4 duplicate; benign)
    {
        int m0w = (wav & 3) * 16;
        f32x4 ga = {0.f, 0.f, 0.f, 0.f};
        #pragma unroll
        for (int kk = 0; kk < 16; ++kk) {
            short8 a = *(const short8*)(Xs + (m0w + l15) * KIN + ((kk * 32 + l4 * 8) ^ swz));
            short8 b = *(const short8*)(WgT + (size_t)l15 * KIN + kk * 32 + l4 * 8);
            ga = __builtin_amdgcn_mfma_f32_16x16x32_bf16(a, b, ga, 0, 0, 0);
        }
        float bias = bg[l15];
        #pragma unroll
        for (int r = 0; r < 4; ++r) {
            float v = ga[r] + bias;
            float m = v;
            m = fmaxf(m, __shfl_xor(m, 1));
            m = fmaxf(m, __shfl_xor(m, 2));
            m = fmaxf(m, __shfl_xor(m, 4));
            float p = __expf(v - m);
            float su = p;
            su += __shfl_xor(su, 1);
            su += __shfl_xor(su, 2);
            su += __shfl_xor(su, 4);
            gs[(m0w + l4 * 4 + r) * 17 + l15] = p / su;
        }
    }
    __syncthreads();                                 // gs visible

    // ---- expert loop state (r10-sized: acc 32 + ti 64 f32)
    f32x4 acc[4][2];
    f32x4 ti0[4][2], ti1[4][2];
    f32x4 z = {0.f, 0.f, 0.f, 0.f};
    #pragma unroll
    for (int mf = 0; mf < 4; ++mf)
        #pragma unroll
        for (int nf = 0; nf < 2; ++nf) { acc[mf][nf] = z; ti0[mf][nf] = z; ti1[mf][nf] = z; }

    auto fold = [&](int e) {
        float b0 = be[e * 256 + wv32 + l15];
        float b1 = be[e * 256 + wv32 + 16 + l15];
        #pragma unroll
        for (int mf = 0; mf < 4; ++mf) {
            #pragma unroll
            for (int r = 0; r < 4; ++r) {
                int rloc = mf * 16 + l4 * 4 + r;
                float g0 = gs[rloc * 17 + e];
                float g1 = gs[rloc * 17 + 8 + e];
                float h0 = fmaxf(acc[mf][0][r] + b0, 0.f);
                float h1 = fmaxf(acc[mf][1][r] + b1, 0.f);
                ti0[mf][0][r] = fmaf(g0, h0, ti0[mf][0][r]);
                ti0[mf][1][r] = fmaf(g0, h1, ti0[mf][1][r]);
                ti1[mf][0][r] = fmaf(g1, h0, ti1[mf][0][r]);
                ti1[mf][1][r] = fmaf(g1, h1, ti1[mf][1][r]);
                acc[mf][0][r] = 0.f;
                acc[mf][1][r] = 0.f;
            }
        }
    };

    // ---- main loop: A from LDS, B transient from L2; no barriers, no DMA
    #pragma unroll 8
    for (int s = 0; s < 64; ++s) {
        int k0 = (s & 7) * 64;
        short8 bb[2][2];                             // transient: lives one step
        #pragma unroll
        for (int kk = 0; kk < 2; ++kk)
            #pragma unroll
            for (int nf = 0; nf < 2; ++nf)
                bb[kk][nf] = *(const short8*)(Wb2 +
                    ((((size_t)(s * 2 + kk) * 8 + wav) * 2 + nf) << 9) + lane * 8);
        __builtin_amdgcn_s_setprio(1);
        #pragma unroll
        for (int kk = 0; kk < 2; ++kk) {
            short8 a[4];
            int kca = (k0 + kk * 32 + l4 * 8) ^ swz;
            #pragma unroll
            for (int mf = 0; mf < 4; ++mf)
                a[mf] = *(const short8*)(Xs + (mf * 16 + l15) * KIN + kca);
            #pragma unroll
            for (int mf = 0; mf < 4; ++mf)
                #pragma unroll
                for (int nf = 0; nf < 2; ++nf)
                    acc[mf][nf] = __builtin_amdgcn_mfma_f32_16x16x32_bf16(
                        a[mf], bb[kk][nf], acc[mf][nf], 0, 0, 0);
        }
        __builtin_amdgcn_s_setprio(0);
        if ((s & 7) == 7) fold(s >> 3);
    }

    // ---- TI -> LDS (bf16), overlaying dead Xs/gs
    __syncthreads();                                 // all waves done with Xs/gs
    #pragma unroll
    for (int mf = 0; mf < 4; ++mf)
        #pragma unroll
        for (int nf = 0; nf < 2; ++nf)
            #pragma unroll
            for (int r = 0; r < 4; ++r) {
                int row = mf * 16 + l4 * 4 + r;
                int col = wv32 + nf * 16 + l15;
                TIs[(0 * 64 + row) * 264 + col] = f2bf(ti0[mf][nf][r]);
                TIs[(1 * 64 + row) * 264 + col] = f2bf(ti1[mf][nf][r]);
            }
    __syncthreads();

    // ---- tower: wave w -> task w>>2, rows (w&3)*16; N=64, K=256
    {
        int tt = wav >> 2, m0t = (wav & 3) * 16;
        f32x4 ac[4];
        #pragma unroll
        for (int nf = 0; nf < 4; ++nf) ac[nf] = z;
        #pragma unroll
        for (int kk = 0; kk < 8; ++kk) {
            int kcol = kk * 32 + l4 * 8;
            short8 a = *(const short8*)(TIs + ((size_t)(tt * 64 + m0t + l15)) * 264 + kcol);
            #pragma unroll
            for (int nf = 0; nf < 4; ++nf) {
                short8 b = *(const short8*)(WtT + ((size_t)tt * NO + nf * 16 + l15) * HE + kcol);
                ac[nf] = __builtin_amdgcn_mfma_f32_16x16x32_bf16(a, b, ac[nf], 0, 0, 0);
            }
        }
        #pragma unroll
        for (int nf = 0; nf < 4; ++nf) {
            int col = nf * 16 + l15;
            float bias = bt[tt * NO + col];
            #pragma unroll
            for (int r = 0; r < 4; ++r) {
                int row = r0 + m0t + l4 * 4 + r;
                float v = ac[nf][r] + bias;
                v = 1.f / (1.f + __expf(-v));
                out[(size_t)tt * (B_ * NO) + (size_t)row * NO + col] = v;
            }
        }
    }
}

extern "C" void kernel_launch(void* const* d_in, const int* in_sizes, int n_in,
                              void* d_out, int out_size, void* d_ws, size_t ws_size,
                              hipStream_t stream) {
    const float* xv = (const float*)d_in[0];
    const float* We = (const float*)d_in[1];
    const float* be = (const float*)d_in[2];
    const float* Wg = (const float*)d_in[3];
    const float* bg = (const float*)d_in[4];
    const float* Wt = (const float*)d_in[5];
    const float* bt = (const float*)d_in[6];
    float* out = (float*)d_out;

    char* w = (char*)d_ws;
    unsigned short* Wb2 = (unsigned short*)(w);                 //  2 MiB
    unsigned short* WtT = (unsigned short*)(w + 2097152);       // 64 KiB
    unsigned short* WgT = (unsigned short*)(w + 2162688);       // 16 KiB

    k_cvt_w<<<265, 256, 0, stream>>>(We, Wt, Wg, Wb2, WtT, WgT);
    k_mega<<<256, 512, 0, stream>>>(xv, Wb2, be, WgT, bg, WtT, bt, out);
}

// Round 17
// 67.227 us; speedup vs baseline: 2.1416x; 2.1416x over previous
//
#include <hip/hip_runtime.h>
#include <hip/hip_bf16.h>

#define B_   16384
#define KIN  512
#define NE   8
#define HE   256
#define NT   2
#define NO   64

using f32x4  = __attribute__((ext_vector_type(4))) float;
using short8 = __attribute__((ext_vector_type(8))) short;

__device__ __forceinline__ float bf2f(unsigned short u) {
    union { unsigned int i; float f; } c; c.i = ((unsigned int)u) << 16; return c.f;
}
__device__ __forceinline__ unsigned short f2bf(float f) {
    union { __hip_bfloat16 h; unsigned short u; } c; c.h = __float2bfloat16(f); return c.u;
}

// ---------------- K_W: weight preprocessing (r11 fragment-major, verified r11-r13,r16) ----------------
// bid < 256: We [E][K][H] -> Wb2 FRAGMENT-MAJOR bf16:
//   Wb2[((((s*2+kk)*8+hg)*2+nf)*64+lane)*8+j] = We[e][kt*64+kk*32+(lane>>4)*8+j][hg*32+nf*16+(lane&15)]
//   with s = e*8+kt. One wave's (s,kk,nf) fragment = contiguous 1KB -> coalesced L2 load.
// bid 256..263: Wt -> WtT bf16 [T][NO][HE];  bid 264: Wg -> WgT bf16 [16][KIN]
__global__ __launch_bounds__(256) void k_cvt_w(const float* __restrict__ We,
                                               const float* __restrict__ Wt,
                                               const float* __restrict__ Wg,
                                               unsigned short* __restrict__ Wb2,
                                               unsigned short* __restrict__ WtT,
                                               unsigned short* __restrict__ WgT) {
    int bid = blockIdx.x;
    int tid = threadIdx.x;
    if (bid < 256) {
        __shared__ float tile[64][65];
        int e = bid >> 5, rem = bid & 31, kt = rem >> 2, ht = rem & 3;
        const float* src = We + e * (KIN * HE) + (kt * 64) * HE + ht * 64;
        for (int it = 0; it < 16; ++it) {
            int idx = tid + it * 256;
            int i = idx >> 6, j = idx & 63;          // i = k-sub, j = h-sub
            tile[i][j] = src[i * HE + j];
        }
        __syncthreads();
        int s = e * 8 + kt;
        for (int it = 0; it < 16; ++it) {
            int o = tid + it * 256;                  // 0..4095 output-linear
            int j = o & 7, lane = (o >> 3) & 63;
            int nf = (o >> 9) & 1, wavl = (o >> 10) & 1, kk = (o >> 11) & 1;
            int l4 = lane >> 4, l15 = lane & 15;
            int ksub = kk * 32 + l4 * 8 + j;
            int hsub = wavl * 32 + nf * 16 + l15;
            size_t F = ((((size_t)(s * 2 + kk) * 8 + (ht * 2 + wavl)) * 2 + nf) * 64 + lane) * 8 + j;
            Wb2[F] = f2bf(tile[ksub][hsub]);
        }
    } else if (bid < 264) {
        __shared__ float tile[64][65];
        int b = bid - 256;
        int t = b >> 2, kt = b & 3, k0 = kt * 64;
        const float* src = Wt + t * (HE * NO) + k0 * NO;
        for (int it = 0; it < 16; ++it) {
            int idx = tid + it * 256;
            int i = idx >> 6, j = idx & 63;
            tile[i][j] = src[i * NO + j];
        }
        __syncthreads();
        unsigned short* dst = WtT + (size_t)t * NO * HE + k0;
        for (int it = 0; it < 16; ++it) {
            int idx = tid + it * 256;
            int o = idx >> 6, j = idx & 63;
            dst[o * HE + j] = f2bf(tile[j][o]);
        }
    } else {
        int n = tid >> 4;
        int kb = (tid & 15) * 32;
        int t = n >> 3, e = n & 7;
        const float* src = Wg + t * (KIN * NE) + e;
        for (int j = 0; j < 32; ++j) {
            int k = kb + j;
            WgT[n * KIN + k] = f2bf(src[k * NE]);
        }
    }
}

// ---------------- K_MEGA: cvt_x + gates + experts + mix + tower ----------------
// B transient from L2 per step (fragment-major Wb2). r16 spilled because
// `#pragma unroll 8` let the scheduler hoist 8 iterations of B-loads (128 VGPR
// in flight) over the ~128 arch-VGPR cap (unified file: ~128 arch + ~128 accum).
// Fix: unroll 2 + sched_barrier(0) per iteration -> live B-loads bounded at 32
// VGPR; in-body overlap (load s+1 || MFMA s) still allowed.
// LDS: Xs 64KB (swizzled) + gs 4.25KB; TIs overlays after the loop.
__global__ __launch_bounds__(512, 2) void k_mega(const float* __restrict__ xv,
                                                 const unsigned short* __restrict__ Wb2,
                                                 const float* __restrict__ be,
                                                 const unsigned short* __restrict__ WgT,
                                                 const float* __restrict__ bg,
                                                 const unsigned short* __restrict__ WtT,
                                                 const float* __restrict__ bt,
                                                 float* __restrict__ out) {
    __shared__ __align__(16) char smem[69888];
    unsigned short* Xs  = (unsigned short*)smem;             // 65536 B, swizzled
    float*          gs  = (float*)(smem + 65536);            // 4352 B, row stride 17
    unsigned short* TIs = (unsigned short*)smem;             // overlay after loop

    int tid = threadIdx.x, lane = tid & 63, wav = tid >> 6;
    int l15 = lane & 15, l4 = lane >> 4;
    int swz = (l15 & 7) * 8;                 // read-side XOR (shorts)
    int wv32 = wav * 32;                     // wave's h-col slice
    int r0 = blockIdx.x * 64;

    // ---- prologue: X fp32 -> bf16 -> swizzled LDS (reg-staged)
    #pragma unroll
    for (int j = 0; j < 8; ++j) {
        int row = wav * 8 + j;
        const float4* src = (const float4*)(xv + (size_t)(r0 + row) * KIN) + lane * 2;
        float4 xa = src[0], xb = src[1];
        union { short8 v; unsigned short s[8]; } cv;
        cv.s[0] = f2bf(xa.x); cv.s[1] = f2bf(xa.y); cv.s[2] = f2bf(xa.z); cv.s[3] = f2bf(xa.w);
        cv.s[4] = f2bf(xb.x); cv.s[5] = f2bf(xb.y); cv.s[6] = f2bf(xb.z); cv.s[7] = f2bf(xb.w);
        *(short8*)(Xs + row * KIN + ((lane ^ (row & 7)) * 8)) = cv.v;
    }
    __syncthreads();                                 // Xs visible

    // ---- gates: softmax(X @ WgT^T + bg) -> gs  (waves w, w+4 duplicate; benign)
    {
        int m0w = (wav & 3) * 16;
        f32x4 ga = {0.f, 0.f, 0.f, 0.f};
        #pragma unroll
        for (int kk = 0; kk < 16; ++kk) {
            short8 a = *(const short8*)(Xs + (m0w + l15) * KIN + ((kk * 32 + l4 * 8) ^ swz));
            short8 b = *(const short8*)(WgT + (size_t)l15 * KIN + kk * 32 + l4 * 8);
            ga = __builtin_amdgcn_mfma_f32_16x16x32_bf16(a, b, ga, 0, 0, 0);
        }
        float bias = bg[l15];
        #pragma unroll
        for (int r = 0; r < 4; ++r) {
            float v = ga[r] + bias;
            float m = v;
            m = fmaxf(m, __shfl_xor(m, 1));
            m = fmaxf(m, __shfl_xor(m, 2));
            m = fmaxf(m, __shfl_xor(m, 4));
            float p = __expf(v - m);
            float su = p;
            su += __shfl_xor(su, 1);
            su += __shfl_xor(su, 2);
            su += __shfl_xor(su, 4);
            gs[(m0w + l4 * 4 + r) * 17 + l15] = p / su;
        }
    }
    __syncthreads();                                 // gs visible

    // ---- expert loop state (r10-sized: acc 32 + ti 64 f32)
    f32x4 acc[4][2];
    f32x4 ti0[4][2], ti1[4][2];
    f32x4 z = {0.f, 0.f, 0.f, 0.f};
    #pragma unroll
    for (int mf = 0; mf < 4; ++mf)
        #pragma unroll
        for (int nf = 0; nf < 2; ++nf) { acc[mf][nf] = z; ti0[mf][nf] = z; ti1[mf][nf] = z; }

    auto fold = [&](int e) {
        float b0 = be[e * 256 + wv32 + l15];
        float b1 = be[e * 256 + wv32 + 16 + l15];
        #pragma unroll
        for (int mf = 0; mf < 4; ++mf) {
            #pragma unroll
            for (int r = 0; r < 4; ++r) {
                int rloc = mf * 16 + l4 * 4 + r;
                float g0 = gs[rloc * 17 + e];
                float g1 = gs[rloc * 17 + 8 + e];
                float h0 = fmaxf(acc[mf][0][r] + b0, 0.f);
                float h1 = fmaxf(acc[mf][1][r] + b1, 0.f);
                ti0[mf][0][r] = fmaf(g0, h0, ti0[mf][0][r]);
                ti0[mf][1][r] = fmaf(g0, h1, ti0[mf][1][r]);
                ti1[mf][0][r] = fmaf(g1, h0, ti1[mf][0][r]);
                ti1[mf][1][r] = fmaf(g1, h1, ti1[mf][1][r]);
                acc[mf][0][r] = 0.f;
                acc[mf][1][r] = 0.f;
            }
        }
    };

    // ---- main loop: A from LDS, B transient from L2.
    // unroll 2 + per-iteration sched_barrier(0): bounds in-flight B-loads to
    // 2 iterations (32 VGPR) — the r16 spill was unroll-8 hoisting 128 VGPRs.
    #pragma unroll 2
    for (int s = 0; s < 64; ++s) {
        int k0 = (s & 7) * 64;
        short8 bb[2][2];                             // transient: lives one step
        #pragma unroll
        for (int kk = 0; kk < 2; ++kk)
            #pragma unroll
            for (int nf = 0; nf < 2; ++nf)
                bb[kk][nf] = *(const short8*)(Wb2 +
                    ((((size_t)(s * 2 + kk) * 8 + wav) * 2 + nf) << 9) + lane * 8);
        __builtin_amdgcn_s_setprio(1);
        #pragma unroll
        for (int kk = 0; kk < 2; ++kk) {
            short8 a[4];
            int kca = (k0 + kk * 32 + l4 * 8) ^ swz;
            #pragma unroll
            for (int mf = 0; mf < 4; ++mf)
                a[mf] = *(const short8*)(Xs + (mf * 16 + l15) * KIN + kca);
            #pragma unroll
            for (int mf = 0; mf < 4; ++mf)
                #pragma unroll
                for (int nf = 0; nf < 2; ++nf)
                    acc[mf][nf] = __builtin_amdgcn_mfma_f32_16x16x32_bf16(
                        a[mf], bb[kk][nf], acc[mf][nf], 0, 0, 0);
        }
        __builtin_amdgcn_s_setprio(0);
        if ((s & 7) == 7) fold(s >> 3);
        __builtin_amdgcn_sched_barrier(0);           // no cross-iteration load hoisting
    }

    // ---- TI -> LDS (bf16), overlaying dead Xs/gs
    __syncthreads();                                 // all waves done with Xs/gs
    #pragma unroll
    for (int mf = 0; mf < 4; ++mf)
        #pragma unroll
        for (int nf = 0; nf < 2; ++nf)
            #pragma unroll
            for (int r = 0; r < 4; ++r) {
                int row = mf * 16 + l4 * 4 + r;
                int col = wv32 + nf * 16 + l15;
                TIs[(0 * 64 + row) * 264 + col] = f2bf(ti0[mf][nf][r]);
                TIs[(1 * 64 + row) * 264 + col] = f2bf(ti1[mf][nf][r]);
            }
    __syncthreads();

    // ---- tower: wave w -> task w>>2, rows (w&3)*16; N=64, K=256
    {
        int tt = wav >> 2, m0t = (wav & 3) * 16;
        f32x4 ac[4];
        #pragma unroll
        for (int nf = 0; nf < 4; ++nf) ac[nf] = z;
        #pragma unroll
        for (int kk = 0; kk < 8; ++kk) {
            int kcol = kk * 32 + l4 * 8;
            short8 a = *(const short8*)(TIs + ((size_t)(tt * 64 + m0t + l15)) * 264 + kcol);
            #pragma unroll
            for (int nf = 0; nf < 4; ++nf) {
                short8 b = *(const short8*)(WtT + ((size_t)tt * NO + nf * 16 + l15) * HE + kcol);
                ac[nf] = __builtin_amdgcn_mfma_f32_16x16x32_bf16(a, b, ac[nf], 0, 0, 0);
            }
        }
        #pragma unroll
        for (int nf = 0; nf < 4; ++nf) {
            int col = nf * 16 + l15;
            float bias = bt[tt * NO + col];
            #pragma unroll
            for (int r = 0; r < 4; ++r) {
                int row = r0 + m0t + l4 * 4 + r;
                float v = ac[nf][r] + bias;
                v = 1.f / (1.f + __expf(-v));
                out[(size_t)tt * (B_ * NO) + (size_t)row * NO + col] = v;
            }
        }
    }
}

extern "C" void kernel_launch(void* const* d_in, const int* in_sizes, int n_in,
                              void* d_out, int out_size, void* d_ws, size_t ws_size,
                              hipStream_t stream) {
    const float* xv = (const float*)d_in[0];
    const float* We = (const float*)d_in[1];
    const float* be = (const float*)d_in[2];
    const float* Wg = (const float*)d_in[3];
    const float* bg = (const float*)d_in[4];
    const float* Wt = (const float*)d_in[5];
    const float* bt = (const float*)d_in[6];
    float* out = (float*)d_out;

    char* w = (char*)d_ws;
    unsigned short* Wb2 = (unsigned short*)(w);                 //  2 MiB
    unsigned short* WtT = (unsigned short*)(w + 2097152);       // 64 KiB
    unsigned short* WgT = (unsigned short*)(w + 2162688);       // 16 KiB

    k_cvt_w<<<265, 256, 0, stream>>>(We, Wt, Wg, Wb2, WtT, WgT);
    k_mega<<<256, 512, 0, stream>>>(xv, Wb2, be, WgT, bg, WtT, bt, out);
}

// Round 18
// 64.435 us; speedup vs baseline: 2.2344x; 1.0433x over previous
//
#include <hip/hip_runtime.h>
#include <hip/hip_bf16.h>

#define B_   16384
#define KIN  512
#define NE   8
#define HE   256
#define NT   2
#define NO   64

using f32x4  = __attribute__((ext_vector_type(4))) float;
using short8 = __attribute__((ext_vector_type(8))) short;

__device__ __forceinline__ float bf2f(unsigned short u) {
    union { unsigned int i; float f; } c; c.i = ((unsigned int)u) << 16; return c.f;
}
__device__ __forceinline__ unsigned short f2bf(float f) {
    union { __hip_bfloat16 h; unsigned short u; } c; c.h = __float2bfloat16(f); return c.u;
}

// ---------------- K_W: weight preprocessing (r11 fragment-major, verified r11-r13,r16,r17) ----------------
// bid < 256: We [E][K][H] -> Wb2 FRAGMENT-MAJOR bf16:
//   Wb2[((((s*2+kk)*8+hg)*2+nf)*64+lane)*8+j] = We[e][kt*64+kk*32+(lane>>4)*8+j][hg*32+nf*16+(lane&15)]
//   with s = e*8+kt. One wave's (s,kk,nf) fragment = contiguous 1KB -> coalesced L2 load.
// bid 256..263: Wt -> WtT bf16 [T][NO][HE];  bid 264: Wg -> WgT bf16 [16][KIN]
__global__ __launch_bounds__(256) void k_cvt_w(const float* __restrict__ We,
                                               const float* __restrict__ Wt,
                                               const float* __restrict__ Wg,
                                               unsigned short* __restrict__ Wb2,
                                               unsigned short* __restrict__ WtT,
                                               unsigned short* __restrict__ WgT) {
    int bid = blockIdx.x;
    int tid = threadIdx.x;
    if (bid < 256) {
        __shared__ float tile[64][65];
        int e = bid >> 5, rem = bid & 31, kt = rem >> 2, ht = rem & 3;
        const float* src = We + e * (KIN * HE) + (kt * 64) * HE + ht * 64;
        for (int it = 0; it < 16; ++it) {
            int idx = tid + it * 256;
            int i = idx >> 6, j = idx & 63;          // i = k-sub, j = h-sub
            tile[i][j] = src[i * HE + j];
        }
        __syncthreads();
        int s = e * 8 + kt;
        for (int it = 0; it < 16; ++it) {
            int o = tid + it * 256;                  // 0..4095 output-linear
            int j = o & 7, lane = (o >> 3) & 63;
            int nf = (o >> 9) & 1, wavl = (o >> 10) & 1, kk = (o >> 11) & 1;
            int l4 = lane >> 4, l15 = lane & 15;
            int ksub = kk * 32 + l4 * 8 + j;
            int hsub = wavl * 32 + nf * 16 + l15;
            size_t F = ((((size_t)(s * 2 + kk) * 8 + (ht * 2 + wavl)) * 2 + nf) * 64 + lane) * 8 + j;
            Wb2[F] = f2bf(tile[ksub][hsub]);
        }
    } else if (bid < 264) {
        __shared__ float tile[64][65];
        int b = bid - 256;
        int t = b >> 2, kt = b & 3, k0 = kt * 64;
        const float* src = Wt + t * (HE * NO) + k0 * NO;
        for (int it = 0; it < 16; ++it) {
            int idx = tid + it * 256;
            int i = idx >> 6, j = idx & 63;
            tile[i][j] = src[i * NO + j];
        }
        __syncthreads();
        unsigned short* dst = WtT + (size_t)t * NO * HE + k0;
        for (int it = 0; it < 16; ++it) {
            int idx = tid + it * 256;
            int o = idx >> 6, j = idx & 63;
            dst[o * HE + j] = f2bf(tile[j][o]);
        }
    } else {
        int n = tid >> 4;
        int kb = (tid & 15) * 32;
        int t = n >> 3, e = n & 7;
        const float* src = Wg + t * (KIN * NE) + e;
        for (int j = 0; j < 32; ++j) {
            int k = kb + j;
            WgT[n * KIN + k] = f2bf(src[k * NE]);
        }
    }
}

// ---------------- K_MEGA: cvt_x + gates + experts + mix + tower ----------------
// B from L2 (fragment-major Wb2) with 1-STEP REGISTER PREFETCH:
// pbuf[2][2][2] parity double buffer, loadB(s+1) issued BEFORE iteration-s MFMAs
// so L2 latency (~300cy) hides under A-reads+MFMAs (~700+cy). Spill-safe per r17:
// #pragma unroll 2 (parity index static, rule #20) + sched_barrier(0) per
// iteration caps in-flight loads at +1 step (~112 VGPR < 128 cap; r17 base = 80).
// r17 (no prefetch) exposed ~1000cy/step of L2 latency -> 62us; this removes it.
// LDS: Xs 64KB (swizzled) + gs 4.25KB; TIs overlays after the loop.
__global__ __launch_bounds__(512, 2) void k_mega(const float* __restrict__ xv,
                                                 const unsigned short* __restrict__ Wb2,
                                                 const float* __restrict__ be,
                                                 const unsigned short* __restrict__ WgT,
                                                 const float* __restrict__ bg,
                                                 const unsigned short* __restrict__ WtT,
                                                 const float* __restrict__ bt,
                                                 float* __restrict__ out) {
    __shared__ __align__(16) char smem[69888];
    unsigned short* Xs  = (unsigned short*)smem;             // 65536 B, swizzled
    float*          gs  = (float*)(smem + 65536);            // 4352 B, row stride 17
    unsigned short* TIs = (unsigned short*)smem;             // overlay after loop

    int tid = threadIdx.x, lane = tid & 63, wav = tid >> 6;
    int l15 = lane & 15, l4 = lane >> 4;
    int swz = (l15 & 7) * 8;                 // read-side XOR (shorts)
    int wv32 = wav * 32;                     // wave's h-col slice
    int r0 = blockIdx.x * 64;

    // ---- prologue: X fp32 -> bf16 -> swizzled LDS (reg-staged)
    #pragma unroll
    for (int j = 0; j < 8; ++j) {
        int row = wav * 8 + j;
        const float4* src = (const float4*)(xv + (size_t)(r0 + row) * KIN) + lane * 2;
        float4 xa = src[0], xb = src[1];
        union { short8 v; unsigned short s[8]; } cv;
        cv.s[0] = f2bf(xa.x); cv.s[1] = f2bf(xa.y); cv.s[2] = f2bf(xa.z); cv.s[3] = f2bf(xa.w);
        cv.s[4] = f2bf(xb.x); cv.s[5] = f2bf(xb.y); cv.s[6] = f2bf(xb.z); cv.s[7] = f2bf(xb.w);
        *(short8*)(Xs + row * KIN + ((lane ^ (row & 7)) * 8)) = cv.v;
    }
    __syncthreads();                                 // Xs visible

    // ---- gates: softmax(X @ WgT^T + bg) -> gs  (waves w, w+4 duplicate; benign)
    {
        int m0w = (wav & 3) * 16;
        f32x4 ga = {0.f, 0.f, 0.f, 0.f};
        #pragma unroll
        for (int kk = 0; kk < 16; ++kk) {
            short8 a = *(const short8*)(Xs + (m0w + l15) * KIN + ((kk * 32 + l4 * 8) ^ swz));
            short8 b = *(const short8*)(WgT + (size_t)l15 * KIN + kk * 32 + l4 * 8);
            ga = __builtin_amdgcn_mfma_f32_16x16x32_bf16(a, b, ga, 0, 0, 0);
        }
        float bias = bg[l15];
        #pragma unroll
        for (int r = 0; r < 4; ++r) {
            float v = ga[r] + bias;
            float m = v;
            m = fmaxf(m, __shfl_xor(m, 1));
            m = fmaxf(m, __shfl_xor(m, 2));
            m = fmaxf(m, __shfl_xor(m, 4));
            float p = __expf(v - m);
            float su = p;
            su += __shfl_xor(su, 1);
            su += __shfl_xor(su, 2);
            su += __shfl_xor(su, 4);
            gs[(m0w + l4 * 4 + r) * 17 + l15] = p / su;
        }
    }
    __syncthreads();                                 // gs visible

    // ---- expert loop state (acc 32 + ti 64 f32)
    f32x4 acc[4][2];
    f32x4 ti0[4][2], ti1[4][2];
    f32x4 z = {0.f, 0.f, 0.f, 0.f};
    #pragma unroll
    for (int mf = 0; mf < 4; ++mf)
        #pragma unroll
        for (int nf = 0; nf < 2; ++nf) { acc[mf][nf] = z; ti0[mf][nf] = z; ti1[mf][nf] = z; }

    auto fold = [&](int e) {
        float b0 = be[e * 256 + wv32 + l15];
        float b1 = be[e * 256 + wv32 + 16 + l15];
        #pragma unroll
        for (int mf = 0; mf < 4; ++mf) {
            #pragma unroll
            for (int r = 0; r < 4; ++r) {
                int rloc = mf * 16 + l4 * 4 + r;
                float g0 = gs[rloc * 17 + e];
                float g1 = gs[rloc * 17 + 8 + e];
                float h0 = fmaxf(acc[mf][0][r] + b0, 0.f);
                float h1 = fmaxf(acc[mf][1][r] + b1, 0.f);
                ti0[mf][0][r] = fmaf(g0, h0, ti0[mf][0][r]);
                ti0[mf][1][r] = fmaf(g0, h1, ti0[mf][1][r]);
                ti1[mf][0][r] = fmaf(g1, h0, ti1[mf][0][r]);
                ti1[mf][1][r] = fmaf(g1, h1, ti1[mf][1][r]);
                acc[mf][0][r] = 0.f;
                acc[mf][1][r] = 0.f;
            }
        }
    };

    auto loadB = [&](int s, short8 (&d)[2][2]) {
        #pragma unroll
        for (int kk = 0; kk < 2; ++kk)
            #pragma unroll
            for (int nf = 0; nf < 2; ++nf)
                d[kk][nf] = *(const short8*)(Wb2 +
                    ((((size_t)(s * 2 + kk) * 8 + wav) * 2 + nf) << 9) + lane * 8);
    };

    // ---- main loop: A from LDS; B from L2 with 1-step parity prefetch
    short8 pbuf[2][2][2];                            // [parity][kk][nf]
    loadB(0, pbuf[0]);
    #pragma unroll 2
    for (int s = 0; s < 64; ++s) {
        const int par = s & 1;                       // static under unroll 2
        if (s < 63) loadB(s + 1, pbuf[par ^ 1]);     // prefetch next step
        int k0 = (s & 7) * 64;
        __builtin_amdgcn_s_setprio(1);
        #pragma unroll
        for (int kk = 0; kk < 2; ++kk) {
            short8 a[4];
            int kca = (k0 + kk * 32 + l4 * 8) ^ swz;
            #pragma unroll
            for (int mf = 0; mf < 4; ++mf)
                a[mf] = *(const short8*)(Xs + (mf * 16 + l15) * KIN + kca);
            #pragma unroll
            for (int mf = 0; mf < 4; ++mf)
                #pragma unroll
                for (int nf = 0; nf < 2; ++nf)
                    acc[mf][nf] = __builtin_amdgcn_mfma_f32_16x16x32_bf16(
                        a[mf], pbuf[par][kk][nf], acc[mf][nf], 0, 0, 0);
        }
        __builtin_amdgcn_s_setprio(0);
        if ((s & 7) == 7) fold(s >> 3);
        __builtin_amdgcn_sched_barrier(0);           // cap hoisting at +1 step
    }

    // ---- TI -> LDS (bf16), overlaying dead Xs/gs
    __syncthreads();                                 // all waves done with Xs/gs
    #pragma unroll
    for (int mf = 0; mf < 4; ++mf)
        #pragma unroll
        for (int nf = 0; nf < 2; ++nf)
            #pragma unroll
            for (int r = 0; r < 4; ++r) {
                int row = mf * 16 + l4 * 4 + r;
                int col = wv32 + nf * 16 + l15;
                TIs[(0 * 64 + row) * 264 + col] = f2bf(ti0[mf][nf][r]);
                TIs[(1 * 64 + row) * 264 + col] = f2bf(ti1[mf][nf][r]);
            }
    __syncthreads();

    // ---- tower: wave w -> task w>>2, rows (w&3)*16; N=64, K=256
    {
        int tt = wav >> 2, m0t = (wav & 3) * 16;
        f32x4 ac[4];
        #pragma unroll
        for (int nf = 0; nf < 4; ++nf) ac[nf] = z;
        #pragma unroll
        for (int kk = 0; kk < 8; ++kk) {
            int kcol = kk * 32 + l4 * 8;
            short8 a = *(const short8*)(TIs + ((size_t)(tt * 64 + m0t + l15)) * 264 + kcol);
            #pragma unroll
            for (int nf = 0; nf < 4; ++nf) {
                short8 b = *(const short8*)(WtT + ((size_t)tt * NO + nf * 16 + l15) * HE + kcol);
                ac[nf] = __builtin_amdgcn_mfma_f32_16x16x32_bf16(a, b, ac[nf], 0, 0, 0);
            }
        }
        #pragma unroll
        for (int nf = 0; nf < 4; ++nf) {
            int col = nf * 16 + l15;
            float bias = bt[tt * NO + col];
            #pragma unroll
            for (int r = 0; r < 4; ++r) {
                int row = r0 + m0t + l4 * 4 + r;
                float v = ac[nf][r] + bias;
                v = 1.f / (1.f + __expf(-v));
                out[(size_t)tt * (B_ * NO) + (size_t)row * NO + col] = v;
            }
        }
    }
}

extern "C" void kernel_launch(void* const* d_in, const int* in_sizes, int n_in,
                              void* d_out, int out_size, void* d_ws, size_t ws_size,
                              hipStream_t stream) {
    const float* xv = (const float*)d_in[0];
    const float* We = (const float*)d_in[1];
    const float* be = (const float*)d_in[2];
    const float* Wg = (const float*)d_in[3];
    const float* bg = (const float*)d_in[4];
    const float* Wt = (const float*)d_in[5];
    const float* bt = (const float*)d_in[6];
    float* out = (float*)d_out;

    char* w = (char*)d_ws;
    unsigned short* Wb2 = (unsigned short*)(w);                 //  2 MiB
    unsigned short* WtT = (unsigned short*)(w + 2097152);       // 64 KiB
    unsigned short* WgT = (unsigned short*)(w + 2162688);       // 16 KiB

    k_cvt_w<<<265, 256, 0, stream>>>(We, Wt, Wg, Wb2, WtT, WgT);
    k_mega<<<256, 512, 0, stream>>>(xv, Wb2, be, WgT, bg, WtT, bt, out);
}